// Round 1
// baseline (1221.664 us; speedup 1.0000x reference)
//
#include <hip/hip_runtime.h>

// Problem constants (from reference)
#define VOCAB 1000000
#define D_IN  256
#define HID   256
#define NCLS  47
#define N0    292864
#define N1    11264
#define N2    1024
#define F0    25
#define F1    10

// ---------------------------------------------------------------------------
// K1: per dst node i in [0,N1): gather self emb row + mean of F0 neighbor
// emb rows into Acat[i] = [self(256) | agg(256)]  (row-major, ld=512).
// Block = 256 threads = one dim each; all row reads are fully coalesced
// (256 threads x 4B = 1KB contiguous).
// ---------------------------------------------------------------------------
__global__ __launch_bounds__(256) void gather_agg0(
    const int* __restrict__ gids0, const int* __restrict__ nbr0,
    const float* __restrict__ emb, float* __restrict__ acat)
{
    const int i = blockIdx.x;
    const int d = threadIdx.x;

    __shared__ int sg[F0];
    __shared__ int selfgid;
    if (d < F0) sg[d] = gids0[nbr0[i * F0 + d]];
    if (d == 0) selfgid = gids0[i];
    __syncthreads();

    const float selfv = emb[(size_t)selfgid * D_IN + d];
    float acc = 0.0f;
#pragma unroll
    for (int j = 0; j < F0; ++j)
        acc += emb[(size_t)sg[j] * D_IN + d];

    acat[(size_t)i * 512 + d]       = selfv;
    acat[(size_t)i * 512 + 256 + d] = acc * (1.0f / F0);
}

// ---------------------------------------------------------------------------
// K2: H = relu(Acat @ [W_self0; W_neigh0] + b0)
// M=11264, K=512, N=256, fp32 (no fp32 MFMA on CDNA4 -> vector SGEMM).
// BM=64, BN=64, BK=32, 256 threads, 4x4 microtile/thread.
// ---------------------------------------------------------------------------
#define BM 64
#define BN 64
#define BK 32

__global__ __launch_bounds__(256) void gemm1_relu(
    const float* __restrict__ A,   // (N1, 512)
    const float* __restrict__ Ws,  // (256, 256)
    const float* __restrict__ Wn,  // (256, 256)
    const float* __restrict__ bias,// (256,)
    float* __restrict__ H)         // (N1, 256)
{
    __shared__ float As[BK][BM + 1]; // k-major, +1 pad to break store conflicts
    __shared__ float Bs[BK][BN];

    const int tid = threadIdx.x;
    const int tx = tid & 15;   // 0..15 -> 4 output cols each
    const int ty = tid >> 4;   // 0..15 -> 4 output rows each
    const int m0 = blockIdx.y * BM;
    const int n0 = blockIdx.x * BN;

    float acc[4][4] = {};

    for (int k0 = 0; k0 < 512; k0 += BK) {
        // B source: rows [k0, k0+BK) of the stacked (512,256) weight matrix.
        // BK=32 divides 256, so a tile never straddles the Ws/Wn boundary.
        const float* Bsrc = (k0 < 256) ? (Ws + (size_t)k0 * 256)
                                       : (Wn + (size_t)(k0 - 256) * 256);
#pragma unroll
        for (int l = 0; l < 2; ++l) {
            const int id = tid + l * 256;
            // A tile: 64 rows x 32 k = 512 float4s; 8 consecutive threads
            // read one row's 8 float4s (128B contiguous).
            const int arow = id >> 3;
            const int akq  = id & 7;
            float4 v = *(const float4*)(A + (size_t)(m0 + arow) * 512 + k0 + akq * 4);
            As[akq * 4 + 0][arow] = v.x;
            As[akq * 4 + 1][arow] = v.y;
            As[akq * 4 + 2][arow] = v.z;
            As[akq * 4 + 3][arow] = v.w;
            // B tile: 32 k-rows x 64 cols; 16 consecutive threads read one
            // k-row's 256B contiguous.
            const int bk  = id >> 4;
            const int bc4 = id & 15;
            float4 w = *(const float4*)(Bsrc + (size_t)bk * 256 + n0 + bc4 * 4);
            *(float4*)&Bs[bk][bc4 * 4] = w;
        }
        __syncthreads();

#pragma unroll
        for (int kk = 0; kk < BK; ++kk) {
            const float a0 = As[kk][ty * 4 + 0];
            const float a1 = As[kk][ty * 4 + 1];
            const float a2 = As[kk][ty * 4 + 2];
            const float a3 = As[kk][ty * 4 + 3];
            const float4 bq = *(const float4*)&Bs[kk][tx * 4];
            acc[0][0] += a0 * bq.x; acc[0][1] += a0 * bq.y; acc[0][2] += a0 * bq.z; acc[0][3] += a0 * bq.w;
            acc[1][0] += a1 * bq.x; acc[1][1] += a1 * bq.y; acc[1][2] += a1 * bq.z; acc[1][3] += a1 * bq.w;
            acc[2][0] += a2 * bq.x; acc[2][1] += a2 * bq.y; acc[2][2] += a2 * bq.z; acc[2][3] += a2 * bq.w;
            acc[3][0] += a3 * bq.x; acc[3][1] += a3 * bq.y; acc[3][2] += a3 * bq.z; acc[3][3] += a3 * bq.w;
        }
        __syncthreads();
    }

    // Epilogue: bias + relu, float4 stores (cols contiguous per thread).
    const int colb = n0 + tx * 4;
    const float4 bv = *(const float4*)(bias + colb);
#pragma unroll
    for (int r = 0; r < 4; ++r) {
        const int row = m0 + ty * 4 + r;
        float4 o;
        o.x = acc[r][0] + bv.x;
        o.y = acc[r][1] + bv.y;
        o.z = acc[r][2] + bv.z;
        o.w = acc[r][3] + bv.w;
        o.x = o.x > 0.0f ? o.x : 0.0f;
        o.y = o.y > 0.0f ? o.y : 0.0f;
        o.z = o.z > 0.0f ? o.z : 0.0f;
        o.w = o.w > 0.0f ? o.w : 0.0f;
        *(float4*)(H + (size_t)row * 256 + colb) = o;
    }
}

// ---------------------------------------------------------------------------
// K3: fused layer 2. One wave per output row i in [0,N2):
//   hcat = [H[i] | mean_j H[nbr1[i,j]]]  (512 floats in LDS)
//   out[i][c] = b1[c] + sum_k hcat[k] * Wcat1[k][c],  c in [0,47)
// Tiny: 24.6 MFLOP total.
// ---------------------------------------------------------------------------
__global__ __launch_bounds__(64) void layer2(
    const float* __restrict__ H,    // (N1, 256)
    const int* __restrict__ nbr1,   // (N2, F1)
    const float* __restrict__ Ws1,  // (256, 47)
    const float* __restrict__ Wn1,  // (256, 47)
    const float* __restrict__ b1,   // (47,)
    float* __restrict__ out)        // (N2, 47)
{
    const int i = blockIdx.x;
    const int lane = threadIdx.x;

    __shared__ float hc[512];
    __shared__ int nb[F1];
    if (lane < F1) nb[lane] = nbr1[i * F1 + lane];
    __syncthreads();

#pragma unroll
    for (int r = 0; r < 4; ++r) {
        const int d = lane + r * 64;
        hc[d] = H[(size_t)i * 256 + d];     // self (i < N2 <= N1)
        float s = 0.0f;
#pragma unroll
        for (int j = 0; j < F1; ++j)
            s += H[(size_t)nb[j] * 256 + d];
        hc[256 + d] = s * (1.0f / F1);
    }
    __syncthreads();

    if (lane < NCLS) {
        float acc = b1[lane];
#pragma unroll 8
        for (int k = 0; k < 256; ++k)
            acc += hc[k] * Ws1[k * NCLS + lane];
#pragma unroll 8
        for (int k = 0; k < 256; ++k)
            acc += hc[256 + k] * Wn1[k * NCLS + lane];
        out[i * NCLS + lane] = acc;
    }
}

// ---------------------------------------------------------------------------
extern "C" void kernel_launch(void* const* d_in, const int* in_sizes, int n_in,
                              void* d_out, int out_size, void* d_ws, size_t ws_size,
                              hipStream_t stream)
{
    const int*   gids0 = (const int*)  d_in[0];
    const int*   nbr0  = (const int*)  d_in[1];
    const int*   nbr1  = (const int*)  d_in[2];
    const float* emb   = (const float*)d_in[3];
    const float* Ws0   = (const float*)d_in[4];
    const float* Wn0   = (const float*)d_in[5];
    const float* b0    = (const float*)d_in[6];
    const float* Ws1   = (const float*)d_in[7];
    const float* Wn1   = (const float*)d_in[8];
    const float* b1    = (const float*)d_in[9];
    float* out = (float*)d_out;

    // Workspace layout: Acat (N1 x 512 f32 = 23.1 MB) | H (N1 x 256 f32 = 11.5 MB)
    float* acat = (float*)d_ws;
    float* H    = acat + (size_t)N1 * 512;

    gather_agg0<<<N1, 256, 0, stream>>>(gids0, nbr0, emb, acat);
    gemm1_relu<<<dim3(HID / BN, N1 / BM), 256, 0, stream>>>(acat, Ws0, Wn0, b0, H);
    layer2<<<N2, 64, 0, stream>>>(H, nbr1, Ws1, Wn1, b1, out);
}